// Round 1
// baseline (738.328 us; speedup 1.0000x reference)
//
#include <hip/hip_runtime.h>
#include <math.h>

#define B_    32
#define REP_  1024
#define NV_   504
#define NR_   190
#define NN_   11538
#define MR_   6
#define HID_  32
#define NH_   4
#define HD_   8
#define MAXN_ 512

// d_out offsets (floats)
#define O_VP   32768
#define O_RN   48896
#define O_NORM 70199936
#define O_VMAX 70199968
#define O_MAXI 70216096

// ws offsets (floats)
#define W_REPT  0
#define W_WT    32768
#define W_PN    401984      // 8 * 194560
#define W_PV    1958464     // 8 * 16128
#define W_N0    2087488
#define W_N1    2282048
#define W_HO    2476608
#define W_MARG  2671168
#define W_RMAX  2677248
#define W_RMAXI 2683328     // int storage

// ---------------------------------------------------------------- transposes
__global__ __launch_bounds__(256) void k_tr_rep(const float* __restrict__ rep,
                                                float* __restrict__ repT) {
    int gid = blockIdx.x * 256 + threadIdx.x;   // 32768 exact
    int b = gid & 31, k = gid >> 5;
    repT[gid] = rep[b * REP_ + k];
}

__global__ __launch_bounds__(256) void k_tr_wn(const float* __restrict__ Wn,
                                               float* __restrict__ Wt) {
    int gid = blockIdx.x * 256 + threadIdx.x;
    if (gid >= NN_ * HID_) return;
    int k = gid & 31, n = gid >> 5;
    Wt[gid] = Wn[k * NN_ + n];
}

// ------------------------------------------------- rep GEMMs (k-split partials)
__global__ __launch_bounds__(256) void k_gemm_node(const float* __restrict__ Wr,
                                                   const float4* __restrict__ repT4,
                                                   float* __restrict__ pn) {
    int c  = blockIdx.x * 64 + (threadIdx.x & 63);   // col < 6080
    int bg = threadIdx.x >> 6;                        // batch group (8 batches)
    int k0 = blockIdx.y * 128;
    float acc[8] = {0.f,0.f,0.f,0.f,0.f,0.f,0.f,0.f};
    int rbase = k0 * 8 + bg * 2;                      // float4 index into repT
    const float* w = Wr + (size_t)k0 * 6080 + c;
    #pragma unroll 4
    for (int k = 0; k < 128; k++) {
        float wv = w[(size_t)k * 6080];
        float4 ra = repT4[rbase + k * 8];
        float4 rb = repT4[rbase + k * 8 + 1];
        acc[0] += ra.x * wv; acc[1] += ra.y * wv; acc[2] += ra.z * wv; acc[3] += ra.w * wv;
        acc[4] += rb.x * wv; acc[5] += rb.y * wv; acc[6] += rb.z * wv; acc[7] += rb.w * wv;
    }
    size_t base = (size_t)blockIdx.y * 194560 + (size_t)(bg * 8) * 6080 + c;
    #pragma unroll
    for (int i = 0; i < 8; i++) pn[base + (size_t)i * 6080] = acc[i];
}

__global__ __launch_bounds__(256) void k_gemm_vp(const float* __restrict__ Wv,
                                                 const float4* __restrict__ repT4,
                                                 float* __restrict__ pv) {
    int c  = blockIdx.x * 64 + (threadIdx.x & 63);
    if (c >= NV_) return;
    int bg = threadIdx.x >> 6;
    int k0 = blockIdx.y * 128;
    float acc[8] = {0.f,0.f,0.f,0.f,0.f,0.f,0.f,0.f};
    int rbase = k0 * 8 + bg * 2;
    const float* w = Wv + (size_t)k0 * NV_ + c;
    #pragma unroll 4
    for (int k = 0; k < 128; k++) {
        float wv = w[(size_t)k * NV_];
        float4 ra = repT4[rbase + k * 8];
        float4 rb = repT4[rbase + k * 8 + 1];
        acc[0] += ra.x * wv; acc[1] += ra.y * wv; acc[2] += ra.z * wv; acc[3] += ra.w * wv;
        acc[4] += rb.x * wv; acc[5] += rb.y * wv; acc[6] += rb.z * wv; acc[7] += rb.w * wv;
    }
    size_t base = (size_t)blockIdx.y * 16128 + (size_t)(bg * 8) * NV_ + c;
    #pragma unroll
    for (int i = 0; i < 8; i++) pv[base + (size_t)i * NV_] = acc[i];
}

__global__ __launch_bounds__(256) void k_reduce(const float* __restrict__ pn,
                                                const float* __restrict__ pv,
                                                const float* __restrict__ br,
                                                const float* __restrict__ bv,
                                                float* __restrict__ node0,
                                                float* __restrict__ vpot) {
    int bid = blockIdx.x, tid = threadIdx.x;
    if (bid < 760) {
        int gid = bid * 256 + tid;                 // enumerates [b][c], c<6080
        int b = gid / 6080, c = gid - b * 6080;
        float s = br[c];
        #pragma unroll
        for (int kz = 0; kz < 8; kz++) s += pn[kz * 194560 + gid];
        node0[(c >> 5) * 1024 + b * 32 + (c & 31)] = s;
    } else {
        int gid = (bid - 760) * 256 + tid;         // enumerates [b][v], v<504
        int v = gid % NV_;
        float s = bv[v];
        #pragma unroll
        for (int kz = 0; kz < 8; kz++) s += pv[kz * 16128 + gid];
        vpot[gid] = s;
    }
}

// ---------------------------------------------------------------- attention
__global__ __launch_bounds__(256) void k_attn(const float* __restrict__ xin,
                                              const float* __restrict__ inw,
                                              const float* __restrict__ inb,
                                              float* __restrict__ ho) {
    int b = blockIdx.x >> 2, h = blockIdx.x & 3;
    int tid = threadIdx.x;
    __shared__ float xs[NR_ * 32];
    __shared__ float wq[24 * 33];
    __shared__ float bq[24];
    __shared__ __align__(16) float qs[NR_ * 8];
    __shared__ __align__(16) float ks[NR_ * 8];
    __shared__ __align__(16) float vs[NR_ * 8];
    __shared__ __align__(16) float ys[NR_ * 8];

    for (int i = tid; i < NR_ * 32; i += 256) {
        int l = i >> 5, e = i & 31;
        xs[i] = xin[l * 1024 + b * 32 + e];
    }
    for (int i = tid; i < 768; i += 256) {
        int j = i >> 5, e = i & 31;
        int row = (j < 8) ? (h * 8 + j) : (j < 16) ? (32 + h * 8 + (j - 8)) : (64 + h * 8 + (j - 16));
        wq[j * 33 + e] = inw[row * 32 + e];
    }
    if (tid < 24) {
        int j = tid;
        int row = (j < 8) ? (h * 8 + j) : (j < 16) ? (32 + h * 8 + (j - 8)) : (64 + h * 8 + (j - 16));
        bq[j] = inb[row];
    }
    __syncthreads();
    for (int i = tid; i < NR_ * 24; i += 256) {
        int t = i / 24, j = i - t * 24;
        float s = bq[j];
        const float* xr = &xs[t * 32];
        const float* wr = &wq[j * 33];
        #pragma unroll
        for (int e = 0; e < 32; e++) s += xr[e] * wr[e];
        float* dst = (j < 8) ? qs : (j < 16) ? ks : vs;
        dst[t * 8 + (j & 7)] = s;
    }
    __syncthreads();
    int wave = tid >> 6, lane = tid & 63;
    const float scale = 0.3535533905932738f;   // 1/sqrt(8)
    for (int l = wave; l < NR_; l += 4) {
        float4 qa = *(const float4*)&qs[l * 8];
        float4 qb = *(const float4*)&qs[l * 8 + 4];
        float sc[3];
        #pragma unroll
        for (int cc = 0; cc < 3; cc++) {
            int m = cc * 64 + lane;
            if (m < NR_) {
                float4 ka = *(const float4*)&ks[m * 8];
                float4 kb = *(const float4*)&ks[m * 8 + 4];
                sc[cc] = (qa.x*ka.x + qa.y*ka.y + qa.z*ka.z + qa.w*ka.w +
                          qb.x*kb.x + qb.y*kb.y + qb.z*kb.z + qb.w*kb.w) * scale;
            } else sc[cc] = -INFINITY;
        }
        float M = fmaxf(sc[0], fmaxf(sc[1], sc[2]));
        #pragma unroll
        for (int off = 32; off > 0; off >>= 1) M = fmaxf(M, __shfl_xor(M, off));
        float p[3], ps = 0.f;
        #pragma unroll
        for (int cc = 0; cc < 3; cc++) { p[cc] = __expf(sc[cc] - M); ps += p[cc]; }
        #pragma unroll
        for (int off = 32; off > 0; off >>= 1) ps += __shfl_xor(ps, off);
        float o[8] = {0.f,0.f,0.f,0.f,0.f,0.f,0.f,0.f};
        #pragma unroll
        for (int cc = 0; cc < 3; cc++) {
            int m = cc * 64 + lane;
            if (m < NR_) {
                float4 va = *(const float4*)&vs[m * 8];
                float4 vb = *(const float4*)&vs[m * 8 + 4];
                float pp = p[cc];
                o[0] += pp*va.x; o[1] += pp*va.y; o[2] += pp*va.z; o[3] += pp*va.w;
                o[4] += pp*vb.x; o[5] += pp*vb.y; o[6] += pp*vb.z; o[7] += pp*vb.w;
            }
        }
        #pragma unroll
        for (int off = 32; off > 0; off >>= 1) {
            #pragma unroll
            for (int d = 0; d < 8; d++) o[d] += __shfl_xor(o[d], off);
        }
        if (lane == 0) {
            float inv = 1.f / ps;
            float4 oa = {o[0]*inv, o[1]*inv, o[2]*inv, o[3]*inv};
            float4 ob = {o[4]*inv, o[5]*inv, o[6]*inv, o[7]*inv};
            *(float4*)&ys[l * 8]     = oa;
            *(float4*)&ys[l * 8 + 4] = ob;
        }
    }
    __syncthreads();
    for (int i = tid; i < NR_ * 8; i += 256) {
        int t = i >> 3, d = i & 7;
        ho[t * 1024 + b * 32 + h * 8 + d] = ys[i];
    }
}

__global__ __launch_bounds__(256) void k_outproj(const float* __restrict__ ho,
                                                 const float* __restrict__ ow,
                                                 const float* __restrict__ ob,
                                                 float* __restrict__ xout) {
    int l = blockIdx.x >> 2, part = blockIdx.x & 3;
    int tid = threadIdx.x;
    __shared__ float w[32 * 33];
    __shared__ float hl[256];
    __shared__ float obs[32];
    for (int i = tid; i < 1024; i += 256) w[(i >> 5) * 33 + (i & 31)] = ow[i];
    if (tid < 32) obs[tid] = ob[tid];
    {
        int bb = tid >> 5, e = tid & 31;
        hl[tid] = ho[l * 1024 + (part * 8 + bb) * 32 + e];
    }
    __syncthreads();
    int bb = tid >> 5, e = tid & 31;
    float s = obs[e];
    #pragma unroll
    for (int e2 = 0; e2 < 32; e2++) s += hl[bb * 32 + e2] * w[e * 33 + e2];
    xout[l * 1024 + (part * 8 + bb) * 32 + e] = s;
}

// ------------------------------------------------------------ big GEMM (280MB)
__global__ __launch_bounds__(256) void k_rnpot(const float* __restrict__ node,
                                               const float* __restrict__ Wn,
                                               const float* __restrict__ bn,
                                               float* __restrict__ out) {
    int tid = threadIdx.x;
    int t0 = blockIdx.x * 64;
    int c0 = blockIdx.y * 256;
    int wave = tid >> 6, lane = tid & 63;
    int c  = c0 + lane * 4;
    int r0 = wave * 16;
    __shared__ float As[64 * 32];
    for (int i = tid; i < 2048; i += 256) As[i] = node[t0 * 32 + i];
    __syncthreads();
    int rem = NN_ - c;
    if (rem >= 4) {
        float a0[16], a1[16], a2[16], a3[16];
        #pragma unroll
        for (int r = 0; r < 16; r++) { a0[r]=0.f; a1[r]=0.f; a2[r]=0.f; a3[r]=0.f; }
        const float* ap = &As[r0 * 32];
        for (int k = 0; k < 32; k++) {
            const float* wp = &Wn[(size_t)k * NN_ + c];
            float2 wa = *(const float2*)wp;
            float2 wb = *(const float2*)(wp + 2);
            #pragma unroll
            for (int r = 0; r < 16; r++) {
                float a = ap[r * 32 + k];
                a0[r] += a * wa.x; a1[r] += a * wa.y; a2[r] += a * wb.x; a3[r] += a * wb.y;
            }
        }
        float b0 = bn[c], b1 = bn[c+1], b2 = bn[c+2], b3 = bn[c+3];
        #pragma unroll
        for (int r = 0; r < 16; r++) {
            size_t base = (size_t)(t0 + r0 + r) * NN_ + c;
            float2 s0 = make_float2(a0[r] + b0, a1[r] + b1);
            float2 s1 = make_float2(a2[r] + b2, a3[r] + b3);
            *(float2*)&out[base]     = s0;
            *(float2*)&out[base + 2] = s1;
        }
    } else if (rem > 0) {
        for (int e = 0; e < rem; e++) {
            float acc[16];
            #pragma unroll
            for (int r = 0; r < 16; r++) acc[r] = 0.f;
            for (int k = 0; k < 32; k++) {
                float wv = Wn[(size_t)k * NN_ + c + e];
                #pragma unroll
                for (int r = 0; r < 16; r++) acc[r] += As[(r0 + r) * 32 + k] * wv;
            }
            float bb = bn[c + e];
            #pragma unroll
            for (int r = 0; r < 16; r++)
                out[(size_t)(t0 + r0 + r) * NN_ + c + e] = acc[r] + bb;
        }
    }
}

// --------------------------------------- grouped gather + max/argmax/logsumexp
__global__ __launch_bounds__(256) void k_grouped(const float* __restrict__ node,
                                                 const float* __restrict__ Wt,
                                                 const float* __restrict__ bn,
                                                 const int* __restrict__ rni,
                                                 float* __restrict__ marg,
                                                 float* __restrict__ rmax,
                                                 int* __restrict__ rmaxi) {
    int l = blockIdx.x;
    int tid = threadIdx.x;
    int jg = tid >> 5, b = tid & 31;
    __shared__ float pm[32 * 8], psum[32 * 8];
    __shared__ int pj[32 * 8];
    float4 nd[8];
    const float4* np = (const float4*)&node[l * 1024 + b * 32];
    #pragma unroll
    for (int q = 0; q < 8; q++) nd[q] = np[q];
    float lm = -INFINITY, ls = 0.f;
    int jm = 0;
    const int* ip = &rni[l * 512];
    for (int jj = 0; jj < 64; jj++) {
        int j = jg * 64 + jj;
        int idx = ip[j];
        const float4* wr = (const float4*)&Wt[idx * 32];
        float s = bn[idx];
        #pragma unroll
        for (int q = 0; q < 8; q++) {
            float4 w4 = wr[q];
            s += nd[q].x*w4.x + nd[q].y*w4.y + nd[q].z*w4.z + nd[q].w*w4.w;
        }
        if (s > lm) { ls = ls * __expf(lm - s) + 1.f; lm = s; jm = j; }
        else        { ls += __expf(s - lm); }
    }
    pm[b * 8 + jg] = lm; psum[b * 8 + jg] = ls; pj[b * 8 + jg] = jm;
    __syncthreads();
    if (tid < 32) {
        int bb = tid;
        float M = pm[bb * 8], S = psum[bb * 8];
        int J = pj[bb * 8];
        for (int i = 1; i < 8; i++) {
            float m2 = pm[bb * 8 + i], s2 = psum[bb * 8 + i];
            if (m2 > M) { S = S * __expf(M - m2) + s2; M = m2; J = pj[bb * 8 + i]; }
            else        { S += s2 * __expf(m2 - M); }
        }
        int t = l * 32 + bb;
        marg[t]  = M + logf(S);
        rmax[t]  = M;
        rmaxi[t] = ip[J];
    }
}

// ---------------------------------------------------------------- final stage
__global__ __launch_bounds__(256) void k_final(const float* __restrict__ marg,
                                               const float* __restrict__ rmax,
                                               const int* __restrict__ rmaxi,
                                               const int* __restrict__ pad,
                                               const float* __restrict__ vpot,
                                               float* __restrict__ out_norm,
                                               float* __restrict__ out_vmax,
                                               float* __restrict__ out_maxi) {
    int b = blockIdx.x, tid = threadIdx.x;
    __shared__ float me[191], xe[191];
    __shared__ int ie[191];
    __shared__ float vm[NV_];
    __shared__ float rbuf[4];
    if (tid < 191) {
        if (tid == 0) { me[0] = 0.f; xe[0] = 0.f; ie[0] = 0; }
        else {
            int t = (tid - 1) * 32 + b;
            me[tid] = marg[t]; xe[tid] = rmax[t]; ie[tid] = rmaxi[t];
        }
    }
    __syncthreads();
    for (int v = tid; v < NV_; v += 256) {
        float sm = 0.f, sx = 0.f;
        float vp = vpot[b * NV_ + v];
        #pragma unroll
        for (int i = 0; i < 6; i++) {
            int p = pad[v * 6 + i];
            sm += me[p]; sx += xe[p];
            out_maxi[(size_t)(b * NV_ + v) * 6 + i] = (float)ie[p];
        }
        vm[v] = sm + vp;
        out_vmax[b * NV_ + v] = sx + vp;
    }
    __syncthreads();
    float m = -INFINITY;
    for (int v = tid; v < NV_; v += 256) m = fmaxf(m, vm[v]);
    #pragma unroll
    for (int off = 32; off > 0; off >>= 1) m = fmaxf(m, __shfl_xor(m, off));
    if ((tid & 63) == 0) rbuf[tid >> 6] = m;
    __syncthreads();
    float M = fmaxf(fmaxf(rbuf[0], rbuf[1]), fmaxf(rbuf[2], rbuf[3]));
    __syncthreads();
    float s = 0.f;
    for (int v = tid; v < NV_; v += 256) s += __expf(vm[v] - M);
    #pragma unroll
    for (int off = 32; off > 0; off >>= 1) s += __shfl_xor(s, off);
    if ((tid & 63) == 0) rbuf[tid >> 6] = s;
    __syncthreads();
    if (tid == 0) out_norm[b] = M + logf(rbuf[0] + rbuf[1] + rbuf[2] + rbuf[3]);
}

// -------------------------------------------------------------------- launch
extern "C" void kernel_launch(void* const* d_in, const int* in_sizes, int n_in,
                              void* d_out, int out_size, void* d_ws, size_t ws_size,
                              hipStream_t stream) {
    const float* rep   = (const float*)d_in[0];
    const float* Wv    = (const float*)d_in[1];
    const float* bv    = (const float*)d_in[2];
    const float* Wr    = (const float*)d_in[3];
    const float* br    = (const float*)d_in[4];
    const float* ainw  = (const float*)d_in[5];
    const float* ainb  = (const float*)d_in[6];
    const float* aoutw = (const float*)d_in[7];
    const float* aoutb = (const float*)d_in[8];
    const float* Wn    = (const float*)d_in[9];
    const float* bn    = (const float*)d_in[10];
    const int*   rni   = (const int*)d_in[11];
    const int*   pad   = (const int*)d_in[12];
    float* out = (float*)d_out;
    float* ws  = (float*)d_ws;

    float* repT = ws + W_REPT;
    float* Wt   = ws + W_WT;
    float* pn   = ws + W_PN;
    float* pv   = ws + W_PV;
    float* n0   = ws + W_N0;
    float* n1   = ws + W_N1;
    float* ho   = ws + W_HO;
    float* marg = ws + W_MARG;
    float* rmx  = ws + W_RMAX;
    int*   rmi  = (int*)(ws + W_RMAXI);

    hipMemcpyAsync(out, rep, 32768 * sizeof(float), hipMemcpyDeviceToDevice, stream);
    k_tr_rep<<<128, 256, 0, stream>>>(rep, repT);
    k_tr_wn<<<1443, 256, 0, stream>>>(Wn, Wt);
    k_gemm_node<<<dim3(95, 8), 256, 0, stream>>>(Wr, (const float4*)repT, pn);
    k_gemm_vp<<<dim3(8, 8), 256, 0, stream>>>(Wv, (const float4*)repT, pv);
    k_reduce<<<823, 256, 0, stream>>>(pn, pv, br, bv, n0, out + O_VP);

    float* bufs[4] = {n0, n1, n0, n1};
    for (int i = 0; i < 3; i++) {
        k_attn<<<128, 256, 0, stream>>>(bufs[i], ainw + i * 96 * 32, ainb + i * 96, ho);
        k_outproj<<<760, 256, 0, stream>>>(ho, aoutw + i * 32 * 32, aoutb + i * 32, bufs[i + 1]);
    }

    k_rnpot<<<dim3(95, 46), 256, 0, stream>>>(n1, Wn, bn, out + O_RN);
    k_grouped<<<190, 256, 0, stream>>>(n1, Wt, bn, rni, marg, rmx, rmi);
    k_final<<<32, 256, 0, stream>>>(marg, rmx, rmi, pad, out + O_VP,
                                    out + O_NORM, out + O_VMAX, out + O_MAXI);
}

// Round 2
// 645.660 us; speedup vs baseline: 1.1435x; 1.1435x over previous
//
#include <hip/hip_runtime.h>
#include <math.h>

#define B_    32
#define REP_  1024
#define NV_   504
#define NR_   190
#define NN_   11538
#define MR_   6
#define HID_  32
#define NH_   4
#define HD_   8
#define MAXN_ 512

// d_out offsets (floats)
#define O_VP   32768
#define O_RN   48896
#define O_NORM 70199936
#define O_VMAX 70199968
#define O_MAXI 70216096

// ws offsets (floats)
#define W_REPT  0
#define W_WT    32768
#define W_PN    401984      // 8 * 194560
#define W_PV    1958464     // 8 * 16128
#define W_N0    2087488
#define W_N1    2282048
#define W_HO    2476608
#define W_MARG  2671168
#define W_RMAX  2677248
#define W_RMAXI 2683328     // int storage

// ---------------------------------------------------------------- transposes
__global__ __launch_bounds__(256) void k_tr_rep(const float* __restrict__ rep,
                                                float* __restrict__ repT) {
    int gid = blockIdx.x * 256 + threadIdx.x;   // 32768 exact
    int b = gid & 31, k = gid >> 5;
    repT[gid] = rep[b * REP_ + k];
}

// 32x32 LDS tile transpose: Wn (32 x 11538) -> Wt (11538 x 32)
__global__ __launch_bounds__(256) void k_tr_wn(const float* __restrict__ Wn,
                                               float* __restrict__ Wt) {
    __shared__ float t[32][33];
    int n0 = blockIdx.x * 32;
    int tid = threadIdx.x;
    #pragma unroll
    for (int p = 0; p < 4; p++) {
        int idx = p * 256 + tid;
        int k = idx >> 5, n = idx & 31;
        int nn = n0 + n;
        t[k][n] = (nn < NN_) ? Wn[(size_t)k * NN_ + nn] : 0.f;
    }
    __syncthreads();
    #pragma unroll
    for (int p = 0; p < 4; p++) {
        int idx = p * 256 + tid;
        int n = idx >> 5, k = idx & 31;
        int nn = n0 + n;
        if (nn < NN_) Wt[nn * 32 + k] = t[k][n];
    }
}

// ------------------------------------------------- rep GEMMs (k-split partials)
__global__ __launch_bounds__(256) void k_gemm_node(const float* __restrict__ Wr,
                                                   const float4* __restrict__ repT4,
                                                   float* __restrict__ pn) {
    int c  = blockIdx.x * 64 + (threadIdx.x & 63);   // col < 6080
    int bg = threadIdx.x >> 6;                        // batch group (8 batches)
    int k0 = blockIdx.y * 128;
    float acc[8] = {0.f,0.f,0.f,0.f,0.f,0.f,0.f,0.f};
    int rbase = k0 * 8 + bg * 2;                      // float4 index into repT
    const float* w = Wr + (size_t)k0 * 6080 + c;
    #pragma unroll 4
    for (int k = 0; k < 128; k++) {
        float wv = w[(size_t)k * 6080];
        float4 ra = repT4[rbase + k * 8];
        float4 rb = repT4[rbase + k * 8 + 1];
        acc[0] += ra.x * wv; acc[1] += ra.y * wv; acc[2] += ra.z * wv; acc[3] += ra.w * wv;
        acc[4] += rb.x * wv; acc[5] += rb.y * wv; acc[6] += rb.z * wv; acc[7] += rb.w * wv;
    }
    size_t base = (size_t)blockIdx.y * 194560 + (size_t)(bg * 8) * 6080 + c;
    #pragma unroll
    for (int i = 0; i < 8; i++) pn[base + (size_t)i * 6080] = acc[i];
}

__global__ __launch_bounds__(256) void k_gemm_vp(const float* __restrict__ Wv,
                                                 const float4* __restrict__ repT4,
                                                 float* __restrict__ pv) {
    int c  = blockIdx.x * 64 + (threadIdx.x & 63);
    if (c >= NV_) return;
    int bg = threadIdx.x >> 6;
    int k0 = blockIdx.y * 128;
    float acc[8] = {0.f,0.f,0.f,0.f,0.f,0.f,0.f,0.f};
    int rbase = k0 * 8 + bg * 2;
    const float* w = Wv + (size_t)k0 * NV_ + c;
    #pragma unroll 4
    for (int k = 0; k < 128; k++) {
        float wv = w[(size_t)k * NV_];
        float4 ra = repT4[rbase + k * 8];
        float4 rb = repT4[rbase + k * 8 + 1];
        acc[0] += ra.x * wv; acc[1] += ra.y * wv; acc[2] += ra.z * wv; acc[3] += ra.w * wv;
        acc[4] += rb.x * wv; acc[5] += rb.y * wv; acc[6] += rb.z * wv; acc[7] += rb.w * wv;
    }
    size_t base = (size_t)blockIdx.y * 16128 + (size_t)(bg * 8) * NV_ + c;
    #pragma unroll
    for (int i = 0; i < 8; i++) pv[base + (size_t)i * NV_] = acc[i];
}

__global__ __launch_bounds__(256) void k_reduce(const float* __restrict__ pn,
                                                const float* __restrict__ pv,
                                                const float* __restrict__ br,
                                                const float* __restrict__ bv,
                                                float* __restrict__ node0,
                                                float* __restrict__ vpot) {
    int bid = blockIdx.x, tid = threadIdx.x;
    if (bid < 760) {
        int gid = bid * 256 + tid;                 // enumerates [b][c], c<6080
        int b = gid / 6080, c = gid - b * 6080;
        float s = br[c];
        #pragma unroll
        for (int kz = 0; kz < 8; kz++) s += pn[kz * 194560 + gid];
        node0[(c >> 5) * 1024 + b * 32 + (c & 31)] = s;
    } else {
        int gid = (bid - 760) * 256 + tid;         // enumerates [b][v], v<504
        int v = gid % NV_;
        float s = bv[v];
        #pragma unroll
        for (int kz = 0; kz < 8; kz++) s += pv[kz * 16128 + gid];
        vpot[gid] = s;
    }
}

// ---------------------------------------------------------------- attention
// One block per (b,h). Phase A: thread t computes q/k/v for role t (weights
// read as wave-uniform scalar loads from global). Phase B: lanes <-> query
// rows (3 per lane), waves split the m-range, online softmax in registers,
// zero shuffles; partials combined through LDS. Writes ho directly.
__global__ __launch_bounds__(256) void k_attn(const float* __restrict__ xin,
                                              const float* __restrict__ inw,
                                              const float* __restrict__ inb,
                                              float* __restrict__ ho) {
    int b = blockIdx.x >> 2, h = blockIdx.x & 3;
    int tid = threadIdx.x;
    __shared__ __align__(16) float qs[192 * 12];
    __shared__ __align__(16) float ks[192 * 12];
    __shared__ __align__(16) float vs[192 * 12];
    __shared__ __align__(16) float pmS[4 * 192];
    __shared__ __align__(16) float psS[4 * 192];
    __shared__ __align__(16) float poS[4 * 192 * 8];

    if (tid < NR_) {
        const float* xr = xin + tid * 1024 + b * 32;
        float4 xv[8];
        #pragma unroll
        for (int q = 0; q < 8; q++) xv[q] = *(const float4*)(xr + q * 4);
        #pragma unroll 1
        for (int part = 0; part < 3; part++) {
            float* dst = (part == 0) ? qs : (part == 1) ? ks : vs;
            #pragma unroll 1
            for (int jj = 0; jj < 8; jj++) {
                int row = part * 32 + h * 8 + jj;      // wave-uniform
                const float* wr = inw + row * 32;
                float s = inb[row];
                #pragma unroll
                for (int q = 0; q < 8; q++) {
                    s += xv[q].x * wr[q*4+0] + xv[q].y * wr[q*4+1] +
                         xv[q].z * wr[q*4+2] + xv[q].w * wr[q*4+3];
                }
                dst[tid * 12 + jj] = s;
            }
        }
    }
    __syncthreads();

    int wave = tid >> 6, lane = tid & 63;
    int m0 = wave * 48;
    int m1 = (m0 + 48 < NR_) ? (m0 + 48) : NR_;
    float4 qa[3], qb[3];
    #pragma unroll
    for (int i = 0; i < 3; i++) {
        int l = lane + 64 * i;
        if (l < NR_) {
            qa[i] = *(const float4*)&qs[l * 12];
            qb[i] = *(const float4*)&qs[l * 12 + 4];
        } else {
            qa[i] = make_float4(0.f,0.f,0.f,0.f);
            qb[i] = make_float4(0.f,0.f,0.f,0.f);
        }
    }
    float mM[3] = {-INFINITY, -INFINITY, -INFINITY};
    float sS[3] = {0.f, 0.f, 0.f};
    float o[3][8];
    #pragma unroll
    for (int i = 0; i < 3; i++)
        #pragma unroll
        for (int d = 0; d < 8; d++) o[i][d] = 0.f;
    const float scale = 0.3535533905932738f;
    for (int mm = m0; mm < m1; mm++) {
        float4 ka = *(const float4*)&ks[mm * 12];
        float4 kb = *(const float4*)&ks[mm * 12 + 4];
        float4 va = *(const float4*)&vs[mm * 12];
        float4 vb = *(const float4*)&vs[mm * 12 + 4];
        #pragma unroll
        for (int i = 0; i < 3; i++) {
            float sc = (qa[i].x*ka.x + qa[i].y*ka.y + qa[i].z*ka.z + qa[i].w*ka.w +
                        qb[i].x*kb.x + qb[i].y*kb.y + qb[i].z*kb.z + qb[i].w*kb.w) * scale;
            if (sc > mM[i]) {
                float al = __expf(mM[i] - sc);   // exp(-inf)=0 on first hit
                sS[i] = sS[i] * al + 1.f;
                mM[i] = sc;
                o[i][0] = o[i][0]*al + va.x; o[i][1] = o[i][1]*al + va.y;
                o[i][2] = o[i][2]*al + va.z; o[i][3] = o[i][3]*al + va.w;
                o[i][4] = o[i][4]*al + vb.x; o[i][5] = o[i][5]*al + vb.y;
                o[i][6] = o[i][6]*al + vb.z; o[i][7] = o[i][7]*al + vb.w;
            } else {
                float p = __expf(sc - mM[i]);
                sS[i] += p;
                o[i][0] += p*va.x; o[i][1] += p*va.y; o[i][2] += p*va.z; o[i][3] += p*va.w;
                o[i][4] += p*vb.x; o[i][5] += p*vb.y; o[i][6] += p*vb.z; o[i][7] += p*vb.w;
            }
        }
    }
    #pragma unroll
    for (int i = 0; i < 3; i++) {
        int slot = wave * 192 + lane + 64 * i;
        pmS[slot] = mM[i];
        psS[slot] = sS[i];
        *(float4*)&poS[slot * 8]     = make_float4(o[i][0], o[i][1], o[i][2], o[i][3]);
        *(float4*)&poS[slot * 8 + 4] = make_float4(o[i][4], o[i][5], o[i][6], o[i][7]);
    }
    __syncthreads();

    if (tid < NR_) {
        float M = pmS[tid], S = psS[tid];
        float4 oa = *(const float4*)&poS[tid * 8];
        float4 ob = *(const float4*)&poS[tid * 8 + 4];
        #pragma unroll
        for (int w = 1; w < 4; w++) {
            int slot = w * 192 + tid;
            float m2 = pmS[slot], s2 = psS[slot];
            float4 pa = *(const float4*)&poS[slot * 8];
            float4 pb = *(const float4*)&poS[slot * 8 + 4];
            if (m2 > M) {
                float al = __expf(M - m2);
                S = S * al + s2;
                oa.x = oa.x*al + pa.x; oa.y = oa.y*al + pa.y; oa.z = oa.z*al + pa.z; oa.w = oa.w*al + pa.w;
                ob.x = ob.x*al + pb.x; ob.y = ob.y*al + pb.y; ob.z = ob.z*al + pb.z; ob.w = ob.w*al + pb.w;
                M = m2;
            } else {
                float p = __expf(m2 - M);
                S += s2 * p;
                oa.x += p*pa.x; oa.y += p*pa.y; oa.z += p*pa.z; oa.w += p*pa.w;
                ob.x += p*pb.x; ob.y += p*pb.y; ob.z += p*pb.z; ob.w += p*pb.w;
            }
        }
        float inv = 1.f / S;
        float* hp = ho + tid * 1024 + b * 32 + h * 8;
        *(float4*)hp       = make_float4(oa.x*inv, oa.y*inv, oa.z*inv, oa.w*inv);
        *(float4*)(hp + 4) = make_float4(ob.x*inv, ob.y*inv, ob.z*inv, ob.w*inv);
    }
}

__global__ __launch_bounds__(256) void k_outproj(const float* __restrict__ ho,
                                                 const float* __restrict__ ow,
                                                 const float* __restrict__ ob,
                                                 float* __restrict__ xout) {
    int l = blockIdx.x >> 2, part = blockIdx.x & 3;
    int tid = threadIdx.x;
    __shared__ float w[32 * 33];
    __shared__ float hl[256];
    __shared__ float obs[32];
    for (int i = tid; i < 1024; i += 256) w[(i >> 5) * 33 + (i & 31)] = ow[i];
    if (tid < 32) obs[tid] = ob[tid];
    {
        int bb = tid >> 5, e = tid & 31;
        hl[tid] = ho[l * 1024 + (part * 8 + bb) * 32 + e];
    }
    __syncthreads();
    int bb = tid >> 5, e = tid & 31;
    float s = obs[e];
    #pragma unroll
    for (int e2 = 0; e2 < 32; e2++) s += hl[bb * 32 + e2] * w[e * 33 + e2];
    xout[l * 1024 + (part * 8 + bb) * 32 + e] = s;
}

// ------------------------------------------------------------ big GEMM (280MB)
// 32 rows x 512 cols per block; 8x8 per thread; A read as b128 broadcasts in
// 4-k groups. Stores are float2 (row stride 11538 is only 8B-aligned).
__global__ __launch_bounds__(256) void k_rnpot(const float* __restrict__ node,
                                               const float* __restrict__ Wn,
                                               const float* __restrict__ bn,
                                               float* __restrict__ out) {
    int tid = threadIdx.x;
    int t0 = blockIdx.x * 32;          // row tile, 190 tiles
    int c0 = blockIdx.y * 512;         // col tile, 23 tiles
    int wave = tid >> 6, lane = tid & 63;
    int r0 = wave * 8;
    int c = c0 + lane * 8;
    __shared__ float As[32 * 32];
    for (int i = tid; i < 1024; i += 256) As[i] = node[t0 * 32 + i];
    __syncthreads();
    int rem = NN_ - c;
    if (rem <= 0) return;
    if (rem >= 8) {
        float acc[8][8];
        #pragma unroll
        for (int r = 0; r < 8; r++)
            #pragma unroll
            for (int q = 0; q < 8; q++) acc[r][q] = 0.f;
        #pragma unroll 1
        for (int g = 0; g < 8; g++) {
            float4 av[8];
            #pragma unroll
            for (int r = 0; r < 8; r++)
                av[r] = *(const float4*)&As[(r0 + r) * 32 + g * 4];
            #pragma unroll
            for (int kk = 0; kk < 4; kk++) {
                int k = g * 4 + kk;
                const float* wp = &Wn[(size_t)k * NN_ + c];
                float2 w0 = *(const float2*)(wp);
                float2 w1 = *(const float2*)(wp + 2);
                float2 w2 = *(const float2*)(wp + 4);
                float2 w3 = *(const float2*)(wp + 6);
                #pragma unroll
                for (int r = 0; r < 8; r++) {
                    float a = ((const float*)&av[r])[kk];
                    acc[r][0] += a * w0.x; acc[r][1] += a * w0.y;
                    acc[r][2] += a * w1.x; acc[r][3] += a * w1.y;
                    acc[r][4] += a * w2.x; acc[r][5] += a * w2.y;
                    acc[r][6] += a * w3.x; acc[r][7] += a * w3.y;
                }
            }
        }
        float bb[8];
        #pragma unroll
        for (int q = 0; q < 8; q++) bb[q] = bn[c + q];
        #pragma unroll
        for (int r = 0; r < 8; r++) {
            size_t base = (size_t)(t0 + r0 + r) * NN_ + c;
            #pragma unroll
            for (int q = 0; q < 4; q++) {
                float2 s = make_float2(acc[r][2*q] + bb[2*q], acc[r][2*q+1] + bb[2*q+1]);
                *(float2*)&out[base + 2*q] = s;
            }
        }
    } else {
        for (int e = 0; e < rem; e++) {
            float acc[8] = {0.f,0.f,0.f,0.f,0.f,0.f,0.f,0.f};
            for (int k = 0; k < 32; k++) {
                float wv = Wn[(size_t)k * NN_ + c + e];
                #pragma unroll
                for (int r = 0; r < 8; r++) acc[r] += As[(r0 + r) * 32 + k] * wv;
            }
            float bv2 = bn[c + e];
            #pragma unroll
            for (int r = 0; r < 8; r++)
                out[(size_t)(t0 + r0 + r) * NN_ + c + e] = acc[r] + bv2;
        }
    }
}

// --------------------------------------- grouped gather + max/argmax/logsumexp
__global__ __launch_bounds__(256) void k_grouped(const float* __restrict__ node,
                                                 const float* __restrict__ Wt,
                                                 const float* __restrict__ bn,
                                                 const int* __restrict__ rni,
                                                 float* __restrict__ marg,
                                                 float* __restrict__ rmax,
                                                 int* __restrict__ rmaxi) {
    int l = blockIdx.x;
    int tid = threadIdx.x;
    int jg = tid >> 5, b = tid & 31;
    __shared__ float pm[32 * 8], psum[32 * 8];
    __shared__ int pj[32 * 8];
    float4 nd[8];
    const float4* np = (const float4*)&node[l * 1024 + b * 32];
    #pragma unroll
    for (int q = 0; q < 8; q++) nd[q] = np[q];
    float lm = -INFINITY, ls = 0.f;
    int jm = 0;
    const int* ip = &rni[l * 512];
    for (int jj = 0; jj < 64; jj++) {
        int j = jg * 64 + jj;
        int idx = ip[j];
        const float4* wr = (const float4*)&Wt[idx * 32];
        float s = bn[idx];
        #pragma unroll
        for (int q = 0; q < 8; q++) {
            float4 w4 = wr[q];
            s += nd[q].x*w4.x + nd[q].y*w4.y + nd[q].z*w4.z + nd[q].w*w4.w;
        }
        if (s > lm) { ls = ls * __expf(lm - s) + 1.f; lm = s; jm = j; }
        else        { ls += __expf(s - lm); }
    }
    pm[b * 8 + jg] = lm; psum[b * 8 + jg] = ls; pj[b * 8 + jg] = jm;
    __syncthreads();
    if (tid < 32) {
        int bb = tid;
        float M = pm[bb * 8], S = psum[bb * 8];
        int J = pj[bb * 8];
        for (int i = 1; i < 8; i++) {
            float m2 = pm[bb * 8 + i], s2 = psum[bb * 8 + i];
            if (m2 > M) { S = S * __expf(M - m2) + s2; M = m2; J = pj[bb * 8 + i]; }
            else        { S += s2 * __expf(m2 - M); }
        }
        int t = l * 32 + bb;
        marg[t]  = M + logf(S);
        rmax[t]  = M;
        rmaxi[t] = ip[J];
    }
}

// ---------------------------------------------------------------- final stage
__global__ __launch_bounds__(256) void k_final(const float* __restrict__ marg,
                                               const float* __restrict__ rmax,
                                               const int* __restrict__ rmaxi,
                                               const int* __restrict__ pad,
                                               const float* __restrict__ vpot,
                                               float* __restrict__ out_norm,
                                               float* __restrict__ out_vmax,
                                               float* __restrict__ out_maxi) {
    int b = blockIdx.x, tid = threadIdx.x;
    __shared__ float me[191], xe[191];
    __shared__ int ie[191];
    __shared__ float vm[NV_];
    __shared__ float rbuf[4];
    if (tid < 191) {
        if (tid == 0) { me[0] = 0.f; xe[0] = 0.f; ie[0] = 0; }
        else {
            int t = (tid - 1) * 32 + b;
            me[tid] = marg[t]; xe[tid] = rmax[t]; ie[tid] = rmaxi[t];
        }
    }
    __syncthreads();
    for (int v = tid; v < NV_; v += 256) {
        float sm = 0.f, sx = 0.f;
        float vp = vpot[b * NV_ + v];
        #pragma unroll
        for (int i = 0; i < 6; i++) {
            int p = pad[v * 6 + i];
            sm += me[p]; sx += xe[p];
            out_maxi[(size_t)(b * NV_ + v) * 6 + i] = (float)ie[p];
        }
        vm[v] = sm + vp;
        out_vmax[b * NV_ + v] = sx + vp;
    }
    __syncthreads();
    float m = -INFINITY;
    for (int v = tid; v < NV_; v += 256) m = fmaxf(m, vm[v]);
    #pragma unroll
    for (int off = 32; off > 0; off >>= 1) m = fmaxf(m, __shfl_xor(m, off));
    if ((tid & 63) == 0) rbuf[tid >> 6] = m;
    __syncthreads();
    float M = fmaxf(fmaxf(rbuf[0], rbuf[1]), fmaxf(rbuf[2], rbuf[3]));
    __syncthreads();
    float s = 0.f;
    for (int v = tid; v < NV_; v += 256) s += __expf(vm[v] - M);
    #pragma unroll
    for (int off = 32; off > 0; off >>= 1) s += __shfl_xor(s, off);
    if ((tid & 63) == 0) rbuf[tid >> 6] = s;
    __syncthreads();
    if (tid == 0) out_norm[b] = M + logf(rbuf[0] + rbuf[1] + rbuf[2] + rbuf[3]);
}

// -------------------------------------------------------------------- launch
extern "C" void kernel_launch(void* const* d_in, const int* in_sizes, int n_in,
                              void* d_out, int out_size, void* d_ws, size_t ws_size,
                              hipStream_t stream) {
    const float* rep   = (const float*)d_in[0];
    const float* Wv    = (const float*)d_in[1];
    const float* bv    = (const float*)d_in[2];
    const float* Wr    = (const float*)d_in[3];
    const float* br    = (const float*)d_in[4];
    const float* ainw  = (const float*)d_in[5];
    const float* ainb  = (const float*)d_in[6];
    const float* aoutw = (const float*)d_in[7];
    const float* aoutb = (const float*)d_in[8];
    const float* Wn    = (const float*)d_in[9];
    const float* bn    = (const float*)d_in[10];
    const int*   rni   = (const int*)d_in[11];
    const int*   pad   = (const int*)d_in[12];
    float* out = (float*)d_out;
    float* ws  = (float*)d_ws;

    float* repT = ws + W_REPT;
    float* Wt   = ws + W_WT;
    float* pn   = ws + W_PN;
    float* pv   = ws + W_PV;
    float* n0   = ws + W_N0;
    float* n1   = ws + W_N1;
    float* ho   = ws + W_HO;
    float* marg = ws + W_MARG;
    float* rmx  = ws + W_RMAX;
    int*   rmi  = (int*)(ws + W_RMAXI);

    hipMemcpyAsync(out, rep, 32768 * sizeof(float), hipMemcpyDeviceToDevice, stream);
    k_tr_rep<<<128, 256, 0, stream>>>(rep, repT);
    k_tr_wn<<<361, 256, 0, stream>>>(Wn, Wt);
    k_gemm_node<<<dim3(95, 8), 256, 0, stream>>>(Wr, (const float4*)repT, pn);
    k_gemm_vp<<<dim3(8, 8), 256, 0, stream>>>(Wv, (const float4*)repT, pv);
    k_reduce<<<823, 256, 0, stream>>>(pn, pv, br, bv, n0, out + O_VP);

    float* bufs[4] = {n0, n1, n0, n1};
    for (int i = 0; i < 3; i++) {
        k_attn<<<128, 256, 0, stream>>>(bufs[i], ainw + i * 96 * 32, ainb + i * 96, ho);
        k_outproj<<<760, 256, 0, stream>>>(ho, aoutw + i * 32 * 32, aoutb + i * 32, bufs[i + 1]);
    }

    k_rnpot<<<dim3(190, 23), 256, 0, stream>>>(n1, Wn, bn, out + O_RN);
    k_grouped<<<190, 256, 0, stream>>>(n1, Wt, bn, rni, marg, rmx, rmi);
    k_final<<<32, 256, 0, stream>>>(marg, rmx, rmi, pad, out + O_VP,
                                    out + O_NORM, out + O_VMAX, out + O_MAXI);
}